// Round 1
// 883.783 us; speedup vs baseline: 1.0418x; 1.0418x over previous
//
#include <hip/hip_runtime.h>
#include <cmath>

// Problem constants
#define S_LEN 2048
#define HID 4096
#define NHEAD 32
#define Q_LORA 1536
#define KV_LORA 512
#define NOPE 128
#define ROPE_D 64
#define VDIM 128
#define QK_DIM 192       // NOPE + ROPE
#define FUSED_N 2112     // Q_LORA + KV_LORA + ROPE
#define FUSED_NPAD 2176  // padded to a multiple of 128

typedef __attribute__((ext_vector_type(8))) short short8;
typedef __attribute__((ext_vector_type(4))) float floatx4;
typedef unsigned short ushort_t;

// float -> bf16 bits, round-to-nearest-even
__device__ inline short f2bf(float f) {
    union { float f; unsigned u; } v; v.f = f;
    unsigned r = (v.u + 0x7fffu + ((v.u >> 16) & 1u)) >> 16;
    return (short)r;
}
__device__ inline float bf2f(ushort_t u) {
    union { unsigned u; float f; } v; v.u = ((unsigned)u) << 16; return v.f;
}

// async 16B global -> LDS (LDS dest: wave-uniform base + lane*16)
#define GLOAD16(g, l)                                                        \
    __builtin_amdgcn_global_load_lds(                                        \
        (const __attribute__((address_space(1))) unsigned int*)(g),          \
        (__attribute__((address_space(3))) unsigned int*)(l), 16, 0, 0)

// ---------------------------------------------------------------------------
// fp32 -> bf16 converters (n % 8 == 0)
// ---------------------------------------------------------------------------
__global__ __launch_bounds__(256) void conv_bf16(
    const float* __restrict__ src, ushort_t* __restrict__ dst, int n)
{
    int i = (blockIdx.x * 256 + threadIdx.x) * 8;
    if (i >= n) return;
    const float4* s = (const float4*)(src + i);
    float4 a = s[0], b = s[1];
    short8 v;
    v[0] = f2bf(a.x); v[1] = f2bf(a.y); v[2] = f2bf(a.z); v[3] = f2bf(a.w);
    v[4] = f2bf(b.x); v[5] = f2bf(b.y); v[6] = f2bf(b.z); v[7] = f2bf(b.w);
    *(short8*)(dst + i) = v;
}

__global__ __launch_bounds__(256) void conv_bf16_pad(
    const float* __restrict__ src, ushort_t* __restrict__ dst, int n_src, int n_tot)
{
    int i = (blockIdx.x * 256 + threadIdx.x) * 8;
    if (i >= n_tot) return;
    short8 v;
    if (i < n_src) {
        const float4* s = (const float4*)(src + i);
        float4 a = s[0], b = s[1];
        v[0] = f2bf(a.x); v[1] = f2bf(a.y); v[2] = f2bf(a.z); v[3] = f2bf(a.w);
        v[4] = f2bf(b.x); v[5] = f2bf(b.y); v[6] = f2bf(b.z); v[7] = f2bf(b.w);
    } else {
        v = (short8){0,0,0,0,0,0,0,0};
    }
    *(short8*)(dst + i) = v;
}

// ---------------------------------------------------------------------------
// bf16 MFMA GEMM (m97 structure): C(M,N) = A(M,K) * B(N,K)^T
// 128x128 tile, BK=32, 4 waves in 2x2, each 64x64 via 4x4 mfma_16x16x32_bf16.
// LDS: fragment-order 16B blocks [rowblock:8][quad:4][lane:16].
// CT = float (fp32 out) or ushort_t (bf16 out). Store guard col < N.
// ---------------------------------------------------------------------------
__device__ inline void store_c(float* p, float v)    { *p = v; }
__device__ inline void store_c(ushort_t* p, float v) { *p = (ushort_t)f2bf(v); }

template <typename CT>
__global__ __launch_bounds__(256) void gemm_bf16(
    const ushort_t* __restrict__ A, int lda,
    const ushort_t* __restrict__ B, int ldb,
    CT* __restrict__ C, int ldc, int N, int K)
{
    __shared__ short8 As8[512];   // 8 KB
    __shared__ short8 Bs8[512];   // 8 KB

    const int tid  = threadIdx.x;
    const int lane = tid & 63;
    const int wave = tid >> 6;
    const int m    = lane & 15;
    const int quad = lane >> 4;
    const int wr   = wave >> 1, wc = wave & 1;
    const int m0 = blockIdx.y * 128;
    const int n0 = blockIdx.x * 128;

    floatx4 acc[4][4];
    #pragma unroll
    for (int i = 0; i < 4; ++i)
        #pragma unroll
        for (int j = 0; j < 4; ++j) acc[i][j] = (floatx4){0.f, 0.f, 0.f, 0.f};

    const int R0 = tid >> 6, q0s = (tid >> 4) & 3, e0 = tid & 15;
    const int R1 = (tid + 256) >> 6, q1s = ((tid + 256) >> 4) & 3, e1 = (tid + 256) & 15;

    for (int k0 = 0; k0 < K; k0 += 32) {
        __syncthreads();
        GLOAD16(A + (size_t)(m0 + R0 * 16 + e0) * lda + k0 + q0s * 8, &As8[tid]);
        GLOAD16(A + (size_t)(m0 + R1 * 16 + e1) * lda + k0 + q1s * 8, &As8[tid + 256]);
        GLOAD16(B + (size_t)(n0 + R0 * 16 + e0) * ldb + k0 + q0s * 8, &Bs8[tid]);
        GLOAD16(B + (size_t)(n0 + R1 * 16 + e1) * ldb + k0 + q1s * 8, &Bs8[tid + 256]);
        __syncthreads();

        short8 af[4], bfr[4];
        #pragma unroll
        for (int i = 0; i < 4; ++i) af[i]  = As8[((wr * 4 + i) * 4 + quad) * 16 + m];
        #pragma unroll
        for (int i = 0; i < 4; ++i) bfr[i] = Bs8[((wc * 4 + i) * 4 + quad) * 16 + m];

        #pragma unroll
        for (int ri = 0; ri < 4; ++ri)
            #pragma unroll
            for (int ci = 0; ci < 4; ++ci)
                acc[ri][ci] = __builtin_amdgcn_mfma_f32_16x16x32_bf16(
                    af[ri], bfr[ci], acc[ri][ci], 0, 0, 0);
    }

    #pragma unroll
    for (int ci = 0; ci < 4; ++ci) {
        int col = n0 + wc * 64 + ci * 16 + m;
        if (col < N) {
            #pragma unroll
            for (int ri = 0; ri < 4; ++ri) {
                int row = m0 + wr * 64 + ri * 16 + quad * 4;
                #pragma unroll
                for (int r = 0; r < 4; ++r)
                    store_c(&C[(size_t)(row + r) * ldc + col], acc[ri][ci][r]);
            }
        }
    }
}

// ---------------------------------------------------------------------------
// RMSNorm(cq), RMSNorm(ckv), RoPE on k_pe — in place on bf16 a (S, 2112).
// ---------------------------------------------------------------------------
__global__ __launch_bounds__(256) void norm_rope_kernel(
    ushort_t* __restrict__ a,
    const float* __restrict__ q_ln_w,
    const float* __restrict__ kv_ln_w,
    const int* __restrict__ pos_ids)
{
    const int s = blockIdx.x;
    ushort_t* row = a + (size_t)s * FUSED_N;
    __shared__ float red[256];
    const int tid = threadIdx.x;

    float ss = 0.f;
    for (int i = tid; i < Q_LORA; i += 256) { float v = bf2f(row[i]); ss += v * v; }
    red[tid] = ss;
    __syncthreads();
    for (int w = 128; w > 0; w >>= 1) {
        if (tid < w) red[tid] += red[tid + w];
        __syncthreads();
    }
    float scale_q = rsqrtf(red[0] / (float)Q_LORA + 1e-6f);
    __syncthreads();
    for (int i = tid; i < Q_LORA; i += 256)
        row[i] = (ushort_t)f2bf(bf2f(row[i]) * scale_q * q_ln_w[i]);
    __syncthreads();

    ss = 0.f;
    for (int i = tid; i < KV_LORA; i += 256) { float v = bf2f(row[Q_LORA + i]); ss += v * v; }
    red[tid] = ss;
    __syncthreads();
    for (int w = 128; w > 0; w >>= 1) {
        if (tid < w) red[tid] += red[tid + w];
        __syncthreads();
    }
    float scale_kv = rsqrtf(red[0] / (float)KV_LORA + 1e-6f);
    __syncthreads();
    for (int i = tid; i < KV_LORA; i += 256)
        row[Q_LORA + i] = (ushort_t)f2bf(bf2f(row[Q_LORA + i]) * scale_kv * kv_ln_w[i]);

    if (tid < 32) {
        const int j = tid;
        float pos = (float)pos_ids[s];
        float inv_freq = expf(-(float)j * (9.210340371976184f / 32.f));
        float ang = pos * inv_freq;
        float c = cosf(ang), sn = sinf(ang);
        float x1 = bf2f(row[Q_LORA + KV_LORA + j]);
        float x2 = bf2f(row[Q_LORA + KV_LORA + 32 + j]);
        row[Q_LORA + KV_LORA + j]      = (ushort_t)f2bf(x1 * c - x2 * sn);
        row[Q_LORA + KV_LORA + 32 + j] = (ushort_t)f2bf(x2 * c + x1 * sn);
    }
}

// ---------------------------------------------------------------------------
// RoPE on q_pe (bf16 in place): q is (S*H, 192), rope dims [128,192)
// ---------------------------------------------------------------------------
__global__ __launch_bounds__(256) void rope_q_kernel(
    ushort_t* __restrict__ q, const int* __restrict__ pos_ids)
{
    int idx = blockIdx.x * blockDim.x + threadIdx.x;
    if (idx >= S_LEN * NHEAD) return;
    int s = idx >> 5;
    float pos = (float)pos_ids[s];
    ushort_t* qp = q + (size_t)idx * QK_DIM + NOPE;
    #pragma unroll 4
    for (int j = 0; j < 32; ++j) {
        float inv_freq = expf(-(float)j * (9.210340371976184f / 32.f));
        float ang = pos * inv_freq;
        float c = cosf(ang), sn = sinf(ang);
        float x1 = bf2f(qp[j]), x2 = bf2f(qp[32 + j]);
        qp[j]      = (ushort_t)f2bf(x1 * c - x2 * sn);
        qp[32 + j] = (ushort_t)f2bf(x2 * c + x1 * sn);
    }
}

// ---------------------------------------------------------------------------
// V pre-transpose: kv (S, H, 256) bf16, v part [128,256) -> vt blocked
// (H, S/8, 128, 8) bf16:  vt[h][g][d][j] = v[key = g*8+j][d]
// This makes the attn V staging a linear, coalesced global_load_lds.
// ---------------------------------------------------------------------------
__global__ __launch_bounds__(256) void transpose_v(
    const ushort_t* __restrict__ kv, ushort_t* __restrict__ vt)
{
    __shared__ ushort_t vs[32][128];   // 8 KB
    const int tid = threadIdx.x;
    const int h   = blockIdx.y;
    const int kb  = blockIdx.x;        // block of 32 keys

    #pragma unroll
    for (int rep = 0; rep < 2; ++rep) {
        int i = rep * 256 + tid;
        int key = i >> 4, ch = i & 15;
        *(short8*)&vs[key][ch * 8] =
            *(const short8*)(kv + ((size_t)(kb * 32 + key) * NHEAD + h) * 256 + 128 + ch * 8);
    }
    __syncthreads();
    #pragma unroll
    for (int rep = 0; rep < 2; ++rep) {
        int i = rep * 256 + tid;
        int kq = i >> 7, d = i & 127;
        short8 v;
        #pragma unroll
        for (int j = 0; j < 8; ++j) v[j] = vs[kq * 8 + j][d];
        *(short8*)(vt + (((size_t)h * (S_LEN / 8) + kb * 4 + kq) * 128 + d) * 8) = v;
    }
}

// ---------------------------------------------------------------------------
// MFMA bf16 flash attention (causal).
//   q:    (S, H, 192) bf16, roped     kv: (S, H, 256) bf16 [k_nope | v]
//   abuf: (S, 2112) bf16, k_pe at 2048
//   vt:   (H, S/8, 128, 8) bf16 pre-transposed V
//   attn: (S, H, 128) bf16
// All K/V staging is async global_load_lds with linear LDS destinations:
//   KF layout [c:6][qd:4][key:32] (read side unchanged), write index
//   decomposed as key=i&31, qd=(i>>5)&3, c=i>>7 so dest is &KF[i].
//   VF is a straight linear copy from the blocked vt.
// ---------------------------------------------------------------------------
__global__ __launch_bounds__(256) void attn_mfma(
    const ushort_t* __restrict__ q,
    const ushort_t* __restrict__ kv,
    const ushort_t* __restrict__ abuf,
    const ushort_t* __restrict__ vt,
    ushort_t* __restrict__ attn)
{
    __shared__ short8 KF[768];
    __shared__ short8 VF[512];
    __shared__ short8 PA[256];

    const int tid  = threadIdx.x;
    const int wave = tid >> 6;
    const int lane = tid & 63;
    const int m    = lane & 15;
    const int quad = lane >> 4;
    const int h    = blockIdx.y;
    // descending work order: longest causal blocks dispatch first
    const int q0   = ((int)gridDim.x - 1 - (int)blockIdx.x) * 64;
    const int qrow_base = q0 + wave * 16;

    short8 qf[6];
    {
        const ushort_t* qrow = q + ((size_t)(qrow_base + m) * NHEAD + h) * QK_DIM;
        #pragma unroll
        for (int c = 0; c < 6; ++c)
            qf[c] = *(const short8*)(qrow + c * 32 + quad * 8);
    }

    floatx4 O[8];
    #pragma unroll
    for (int t = 0; t < 8; ++t) O[t] = (floatx4){0.f, 0.f, 0.f, 0.f};
    float mrow[4] = {-1e30f, -1e30f, -1e30f, -1e30f};
    float lrow[4] = {0.f, 0.f, 0.f, 0.f};

    const float scale = 0.07216878364870323f; // 1/sqrt(192)
    const int ntile = (q0 + 64) / 32;
    short* pas = (short*)PA;

    for (int tt = 0; tt < ntile; ++tt) {
        const int t0 = tt * 32;
        __syncthreads();

        // K (k_nope c=0..3 from kv, k_pe c=4..5 from abuf): linear LDS dest
        #pragma unroll
        for (int rep = 0; rep < 3; ++rep) {
            int i   = rep * 256 + tid;
            int key = i & 31, qd = (i >> 5) & 3, c = i >> 7;
            if (c < 4)
                GLOAD16(kv + ((size_t)(t0 + key) * NHEAD + h) * 256 + c * 32 + qd * 8,
                        &KF[i]);
            else
                GLOAD16(abuf + (size_t)(t0 + key) * FUSED_N + 2048 + (c - 4) * 32 + qd * 8,
                        &KF[i]);
        }
        // V: linear + fully coalesced from blocked vt
        {
            const ushort_t* vsrc = vt + ((size_t)h * (S_LEN / 8) + (t0 >> 3)) * 1024;
            GLOAD16(vsrc + (size_t)tid * 8, &VF[tid]);
            GLOAD16(vsrc + (size_t)(256 + tid) * 8, &VF[256 + tid]);
        }
        __syncthreads();

        floatx4 s0 = (floatx4){0.f, 0.f, 0.f, 0.f};
        floatx4 s1 = (floatx4){0.f, 0.f, 0.f, 0.f};
        const int kb = quad * 32 + m;
        #pragma unroll
        for (int c = 0; c < 6; ++c) {
            s0 = __builtin_amdgcn_mfma_f32_16x16x32_bf16(qf[c], KF[c * 128 + kb],      s0, 0, 0, 0);
            s1 = __builtin_amdgcn_mfma_f32_16x16x32_bf16(qf[c], KF[c * 128 + kb + 16], s1, 0, 0, 0);
        }

        const int qb = qrow_base + quad * 4;
        float sv0[4], sv1[4];
        #pragma unroll
        for (int r = 0; r < 4; ++r) {
            float a0 = s0[r] * scale;
            float a1 = s1[r] * scale;
            if (t0 + m > qb + r)      a0 = -1e30f;
            if (t0 + 16 + m > qb + r) a1 = -1e30f;
            sv0[r] = a0; sv1[r] = a1;
        }
        #pragma unroll
        for (int r = 0; r < 4; ++r) {
            float v = fmaxf(sv0[r], sv1[r]);
            v = fmaxf(v, __shfl_xor(v, 1));
            v = fmaxf(v, __shfl_xor(v, 2));
            v = fmaxf(v, __shfl_xor(v, 4));
            v = fmaxf(v, __shfl_xor(v, 8));
            float mnew  = fmaxf(mrow[r], v);
            float alpha = __expf(mrow[r] - mnew);
            float p0 = __expf(sv0[r] - mnew);
            float p1 = __expf(sv1[r] - mnew);
            float rs = p0 + p1;
            rs += __shfl_xor(rs, 1);
            rs += __shfl_xor(rs, 2);
            rs += __shfl_xor(rs, 4);
            rs += __shfl_xor(rs, 8);
            lrow[r] = lrow[r] * alpha + rs;
            mrow[r] = mnew;
            #pragma unroll
            for (int t = 0; t < 8; ++t) O[t][r] *= alpha;
            int row = quad * 4 + r;
            short* pw = pas + wave * 512;
            pw[((m >> 3) + 0) * 128 + row * 8 + (m & 7)] = f2bf(p0);
            pw[((m >> 3) + 2) * 128 + row * 8 + (m & 7)] = f2bf(p1);
        }

        short8 pfrag = PA[wave * 64 + quad * 16 + m];
        #pragma unroll
        for (int t = 0; t < 8; ++t) {
            O[t] = __builtin_amdgcn_mfma_f32_16x16x32_bf16(
                pfrag, VF[quad * 128 + m + 16 * t], O[t], 0, 0, 0);
        }
    }

    #pragma unroll
    for (int r = 0; r < 4; ++r) {
        float linv = 1.f / lrow[r];
        int row = qrow_base + quad * 4 + r;
        ushort_t* dst = attn + ((size_t)row * NHEAD + h) * VDIM + m;
        #pragma unroll
        for (int t = 0; t < 8; ++t)
            dst[16 * t] = (ushort_t)f2bf(O[t][r] * linv);
    }
}

// ---------------------------------------------------------------------------
extern "C" void kernel_launch(void* const* d_in, const int* in_sizes, int n_in,
                              void* d_out, int out_size, void* d_ws, size_t ws_size,
                              hipStream_t stream)
{
    const int*   pos    = (const int*)d_in[0];
    const float* hs     = (const float*)d_in[1];
    const float* w_a    = (const float*)d_in[2];
    const float* qlnw   = (const float*)d_in[3];
    const float* kvlnw  = (const float*)d_in[4];
    const float* w_qb   = (const float*)d_in[5];
    const float* w_kvb  = (const float*)d_in[6];
    const float* w_o    = (const float*)d_in[7];
    float* out = (float*)d_out;

    // workspace layout — all bf16, 146.0 MB total
    char* p = (char*)d_ws;
    ushort_t* a_bf    = (ushort_t*)p; p += (size_t)S_LEN * FUSED_N * 2;          //  8.65 MB
    ushort_t* q_bf    = (ushort_t*)p; p += (size_t)S_LEN * NHEAD * QK_DIM * 2;   // 25.2 MB
    ushort_t* kv_bf   = (ushort_t*)p; p += (size_t)S_LEN * NHEAD * 256 * 2;      // 33.6 MB
    ushort_t* attn_bf = (ushort_t*)p; p += (size_t)S_LEN * HID * 2;              // 16.8 MB
    ushort_t* hs_bf   = (ushort_t*)p; p += (size_t)S_LEN * HID * 2;              // 16.8 MB
    ushort_t* w_a_bf  = (ushort_t*)p; p += (size_t)FUSED_NPAD * HID * 2;         // 17.8 MB
    ushort_t* w_qb_bf = (ushort_t*)p; p += (size_t)NHEAD * QK_DIM * Q_LORA * 2;  // 18.9 MB
    ushort_t* w_kvb_bf= (ushort_t*)p; p += (size_t)NHEAD * 256 * KV_LORA * 2;    //  8.4 MB
    // w_o_bf (33.6 MB) aliases hs_bf + w_a_bf (34.6 MB), both dead after gemm 1
    ushort_t* w_o_bf  = hs_bf;
    // vt (16.8 MB) aliases w_qb_bf (18.9 MB), dead after gemm 3
    ushort_t* vt_bf   = w_qb_bf;

    if (ws_size < (size_t)(p - (char*)d_ws)) return;  // fail loud, not fault

    dim3 blk(256);
    auto cgrid = [](size_t n) { return dim3((unsigned)((n / 8 + 255) / 256)); };

    // 0. fp32 -> bf16 (hs + weights for gemms 1,3,4)
    conv_bf16<<<cgrid((size_t)S_LEN * HID), blk, 0, stream>>>(hs, hs_bf, S_LEN * HID);
    conv_bf16_pad<<<cgrid((size_t)FUSED_NPAD * HID), blk, 0, stream>>>(
        w_a, w_a_bf, FUSED_N * HID, FUSED_NPAD * HID);
    conv_bf16<<<cgrid((size_t)NHEAD * QK_DIM * Q_LORA), blk, 0, stream>>>(
        w_qb, w_qb_bf, NHEAD * QK_DIM * Q_LORA);
    conv_bf16<<<cgrid((size_t)NHEAD * 256 * KV_LORA), blk, 0, stream>>>(
        w_kvb, w_kvb_bf, NHEAD * 256 * KV_LORA);

    // 1. a = hs @ w_fused_a^T : (2048, 2112) bf16, K=4096
    gemm_bf16<ushort_t><<<dim3(FUSED_NPAD / 128, S_LEN / 128), blk, 0, stream>>>(
        hs_bf, HID, w_a_bf, HID, a_bf, FUSED_N, FUSED_N, HID);

    // 1b. w_o -> bf16 (into region freed by gemm 1)
    conv_bf16<<<cgrid((size_t)HID * HID), blk, 0, stream>>>(w_o, w_o_bf, HID * HID);

    // 2. RMSNorm cq / ckv + k_pe RoPE (in place, bf16)
    norm_rope_kernel<<<S_LEN, 256, 0, stream>>>(a_bf, qlnw, kvlnw, pos);

    // 3. q = cq @ w_q_b^T : (2048, 6144) bf16, K=1536
    gemm_bf16<ushort_t><<<dim3(NHEAD * QK_DIM / 128, S_LEN / 128), blk, 0, stream>>>(
        a_bf, FUSED_N, w_qb_bf, Q_LORA, q_bf, NHEAD * QK_DIM, NHEAD * QK_DIM, Q_LORA);

    // 4. kv = ckv @ w_kv_b^T : (2048, 8192) bf16, K=512
    gemm_bf16<ushort_t><<<dim3(NHEAD * 256 / 128, S_LEN / 128), blk, 0, stream>>>(
        a_bf + Q_LORA, FUSED_N, w_kvb_bf, KV_LORA, kv_bf, NHEAD * 256, NHEAD * 256, KV_LORA);

    // 4b. V pre-transpose into blocked (H, S/8, 128, 8) — w_qb region now dead
    transpose_v<<<dim3(S_LEN / 32, NHEAD), blk, 0, stream>>>(kv_bf, vt_bf);

    // 5. RoPE on q_pe (bf16 in place)
    rope_q_kernel<<<(S_LEN * NHEAD + 255) / 256, 256, 0, stream>>>(q_bf, pos);

    // 6. MFMA flash attention -> attn (2048, 32, 128) bf16
    attn_mfma<<<dim3(S_LEN / 64, NHEAD), blk, 0, stream>>>(
        q_bf, kv_bf, a_bf, vt_bf, attn_bf);

    // 7. out = attn @ w_o^T : (2048, 4096) fp32, K=4096
    gemm_bf16<float><<<dim3(HID / 128, S_LEN / 128), blk, 0, stream>>>(
        attn_bf, HID, w_o_bf, HID, out, HID, HID, HID);
}

// Round 2
// 757.533 us; speedup vs baseline: 1.2154x; 1.1667x over previous
//
#include <hip/hip_runtime.h>
#include <cmath>

// Problem constants
#define S_LEN 2048
#define HID 4096
#define NHEAD 32
#define Q_LORA 1536
#define KV_LORA 512
#define NOPE 128
#define ROPE_D 64
#define VDIM 128
#define QK_DIM 192       // NOPE + ROPE
#define FUSED_N 2112     // Q_LORA + KV_LORA + ROPE
#define FUSED_NPAD 2176  // padded to a multiple of 128

typedef __attribute__((ext_vector_type(8))) short short8;
typedef __attribute__((ext_vector_type(4))) float floatx4;
typedef unsigned short ushort_t;

// float -> bf16 bits, round-to-nearest-even
__device__ inline short f2bf(float f) {
    union { float f; unsigned u; } v; v.f = f;
    unsigned r = (v.u + 0x7fffu + ((v.u >> 16) & 1u)) >> 16;
    return (short)r;
}
__device__ inline float bf2f(ushort_t u) {
    union { unsigned u; float f; } v; v.u = ((unsigned)u) << 16; return v.f;
}

// async 16B global -> LDS (LDS dest: wave-uniform base + lane*16)
#define GLOAD16(g, l)                                                        \
    __builtin_amdgcn_global_load_lds(                                        \
        (const __attribute__((address_space(1))) unsigned int*)(g),          \
        (__attribute__((address_space(3))) unsigned int*)(l), 16, 0, 0)

// ---------------------------------------------------------------------------
// fp32 -> bf16 converters (n % 8 == 0)
// ---------------------------------------------------------------------------
__global__ __launch_bounds__(256) void conv_bf16(
    const float* __restrict__ src, ushort_t* __restrict__ dst, int n)
{
    int i = (blockIdx.x * 256 + threadIdx.x) * 8;
    if (i >= n) return;
    const float4* s = (const float4*)(src + i);
    float4 a = s[0], b = s[1];
    short8 v;
    v[0] = f2bf(a.x); v[1] = f2bf(a.y); v[2] = f2bf(a.z); v[3] = f2bf(a.w);
    v[4] = f2bf(b.x); v[5] = f2bf(b.y); v[6] = f2bf(b.z); v[7] = f2bf(b.w);
    *(short8*)(dst + i) = v;
}

__global__ __launch_bounds__(256) void conv_bf16_pad(
    const float* __restrict__ src, ushort_t* __restrict__ dst, int n_src, int n_tot)
{
    int i = (blockIdx.x * 256 + threadIdx.x) * 8;
    if (i >= n_tot) return;
    short8 v;
    if (i < n_src) {
        const float4* s = (const float4*)(src + i);
        float4 a = s[0], b = s[1];
        v[0] = f2bf(a.x); v[1] = f2bf(a.y); v[2] = f2bf(a.z); v[3] = f2bf(a.w);
        v[4] = f2bf(b.x); v[5] = f2bf(b.y); v[6] = f2bf(b.z); v[7] = f2bf(b.w);
    } else {
        v = (short8){0,0,0,0,0,0,0,0};
    }
    *(short8*)(dst + i) = v;
}

// ---------------------------------------------------------------------------
// bf16 MFMA GEMM, 2-phase pipelined (issue-early / drain-late):
// C(M,N) = A(M,K) * B(N,K)^T, 128x128 tile, BK=32, 4 waves 2x2.
// Double-buffered LDS; next K-step's global_load_lds issued BEFORE computing
// the current one, single __syncthreads per step (loads fly during compute).
// ---------------------------------------------------------------------------
__device__ inline void store_c(float* p, float v)    { *p = v; }
__device__ inline void store_c(ushort_t* p, float v) { *p = (ushort_t)f2bf(v); }

template <typename CT>
__global__ __launch_bounds__(256) void gemm_bf16(
    const ushort_t* __restrict__ A, int lda,
    const ushort_t* __restrict__ B, int ldb,
    CT* __restrict__ C, int ldc, int N, int K)
{
    __shared__ short8 As8[2][512];   // 16 KB
    __shared__ short8 Bs8[2][512];   // 16 KB

    const int tid  = threadIdx.x;
    const int lane = tid & 63;
    const int wave = tid >> 6;
    const int m    = lane & 15;
    const int quad = lane >> 4;
    const int wr   = wave >> 1, wc = wave & 1;
    const int m0 = blockIdx.y * 128;
    const int n0 = blockIdx.x * 128;

    floatx4 acc[4][4];
    #pragma unroll
    for (int i = 0; i < 4; ++i)
        #pragma unroll
        for (int j = 0; j < 4; ++j) acc[i][j] = (floatx4){0.f, 0.f, 0.f, 0.f};

    const int R0 = tid >> 6, q0s = (tid >> 4) & 3, e0 = tid & 15;
    const int R1 = (tid + 256) >> 6, q1s = ((tid + 256) >> 4) & 3, e1 = (tid + 256) & 15;

    auto stage = [&](int k0, int buf) {
        GLOAD16(A + (size_t)(m0 + R0 * 16 + e0) * lda + k0 + q0s * 8, &As8[buf][tid]);
        GLOAD16(A + (size_t)(m0 + R1 * 16 + e1) * lda + k0 + q1s * 8, &As8[buf][tid + 256]);
        GLOAD16(B + (size_t)(n0 + R0 * 16 + e0) * ldb + k0 + q0s * 8, &Bs8[buf][tid]);
        GLOAD16(B + (size_t)(n0 + R1 * 16 + e1) * ldb + k0 + q1s * 8, &Bs8[buf][tid + 256]);
    };

    stage(0, 0);
    __syncthreads();
    int cur = 0;

    for (int k0 = 0; k0 < K; k0 += 32) {
        if (k0 + 32 < K) stage(k0 + 32, cur ^ 1);

        short8 af[4], bfr[4];
        #pragma unroll
        for (int i = 0; i < 4; ++i) af[i]  = As8[cur][((wr * 4 + i) * 4 + quad) * 16 + m];
        #pragma unroll
        for (int i = 0; i < 4; ++i) bfr[i] = Bs8[cur][((wc * 4 + i) * 4 + quad) * 16 + m];

        #pragma unroll
        for (int ri = 0; ri < 4; ++ri)
            #pragma unroll
            for (int ci = 0; ci < 4; ++ci)
                acc[ri][ci] = __builtin_amdgcn_mfma_f32_16x16x32_bf16(
                    af[ri], bfr[ci], acc[ri][ci], 0, 0, 0);

        __syncthreads();   // drains vmcnt(0)+lgkmcnt(0): next buf ready, cur reads done
        cur ^= 1;
    }

    #pragma unroll
    for (int ci = 0; ci < 4; ++ci) {
        int col = n0 + wc * 64 + ci * 16 + m;
        if (col < N) {
            #pragma unroll
            for (int ri = 0; ri < 4; ++ri) {
                int row = m0 + wr * 64 + ri * 16 + quad * 4;
                #pragma unroll
                for (int r = 0; r < 4; ++r)
                    store_c(&C[(size_t)(row + r) * ldc + col], acc[ri][ci][r]);
            }
        }
    }
}

// ---------------------------------------------------------------------------
// RMSNorm(cq), RMSNorm(ckv), RoPE on k_pe — in place on bf16 a (S, 2112).
// ---------------------------------------------------------------------------
__global__ __launch_bounds__(256) void norm_rope_kernel(
    ushort_t* __restrict__ a,
    const float* __restrict__ q_ln_w,
    const float* __restrict__ kv_ln_w,
    const int* __restrict__ pos_ids)
{
    const int s = blockIdx.x;
    ushort_t* row = a + (size_t)s * FUSED_N;
    __shared__ float red[256];
    const int tid = threadIdx.x;

    float ss = 0.f;
    for (int i = tid; i < Q_LORA; i += 256) { float v = bf2f(row[i]); ss += v * v; }
    red[tid] = ss;
    __syncthreads();
    for (int w = 128; w > 0; w >>= 1) {
        if (tid < w) red[tid] += red[tid + w];
        __syncthreads();
    }
    float scale_q = rsqrtf(red[0] / (float)Q_LORA + 1e-6f);
    __syncthreads();
    for (int i = tid; i < Q_LORA; i += 256)
        row[i] = (ushort_t)f2bf(bf2f(row[i]) * scale_q * q_ln_w[i]);
    __syncthreads();

    ss = 0.f;
    for (int i = tid; i < KV_LORA; i += 256) { float v = bf2f(row[Q_LORA + i]); ss += v * v; }
    red[tid] = ss;
    __syncthreads();
    for (int w = 128; w > 0; w >>= 1) {
        if (tid < w) red[tid] += red[tid + w];
        __syncthreads();
    }
    float scale_kv = rsqrtf(red[0] / (float)KV_LORA + 1e-6f);
    __syncthreads();
    for (int i = tid; i < KV_LORA; i += 256)
        row[Q_LORA + i] = (ushort_t)f2bf(bf2f(row[Q_LORA + i]) * scale_kv * kv_ln_w[i]);

    if (tid < 32) {
        const int j = tid;
        float pos = (float)pos_ids[s];
        float inv_freq = expf(-(float)j * (9.210340371976184f / 32.f));
        float ang = pos * inv_freq;
        float c = cosf(ang), sn = sinf(ang);
        float x1 = bf2f(row[Q_LORA + KV_LORA + j]);
        float x2 = bf2f(row[Q_LORA + KV_LORA + 32 + j]);
        row[Q_LORA + KV_LORA + j]      = (ushort_t)f2bf(x1 * c - x2 * sn);
        row[Q_LORA + KV_LORA + 32 + j] = (ushort_t)f2bf(x2 * c + x1 * sn);
    }
}

// ---------------------------------------------------------------------------
// RoPE on q_pe (bf16 in place): q is (S*H, 192), rope dims [128,192)
// ---------------------------------------------------------------------------
__global__ __launch_bounds__(256) void rope_q_kernel(
    ushort_t* __restrict__ q, const int* __restrict__ pos_ids)
{
    int idx = blockIdx.x * blockDim.x + threadIdx.x;
    if (idx >= S_LEN * NHEAD) return;
    int s = idx >> 5;
    float pos = (float)pos_ids[s];
    ushort_t* qp = q + (size_t)idx * QK_DIM + NOPE;
    #pragma unroll 4
    for (int j = 0; j < 32; ++j) {
        float inv_freq = expf(-(float)j * (9.210340371976184f / 32.f));
        float ang = pos * inv_freq;
        float c = cosf(ang), sn = sinf(ang);
        float x1 = bf2f(qp[j]), x2 = bf2f(qp[32 + j]);
        qp[j]      = (ushort_t)f2bf(x1 * c - x2 * sn);
        qp[32 + j] = (ushort_t)f2bf(x2 * c + x1 * sn);
    }
}

// ---------------------------------------------------------------------------
// V pre-transpose: kv (S, H, 256) bf16, v part [128,256) -> vt blocked
// (H, S/8, 128, 8) bf16:  vt[h][g][d][j] = v[key = g*8+j][d]
// ---------------------------------------------------------------------------
__global__ __launch_bounds__(256) void transpose_v(
    const ushort_t* __restrict__ kv, ushort_t* __restrict__ vt)
{
    __shared__ ushort_t vs[32][128];   // 8 KB
    const int tid = threadIdx.x;
    const int h   = blockIdx.y;
    const int kb  = blockIdx.x;        // block of 32 keys

    #pragma unroll
    for (int rep = 0; rep < 2; ++rep) {
        int i = rep * 256 + tid;
        int key = i >> 4, ch = i & 15;
        *(short8*)&vs[key][ch * 8] =
            *(const short8*)(kv + ((size_t)(kb * 32 + key) * NHEAD + h) * 256 + 128 + ch * 8);
    }
    __syncthreads();
    #pragma unroll
    for (int rep = 0; rep < 2; ++rep) {
        int i = rep * 256 + tid;
        int kq = i >> 7, d = i & 127;
        short8 v;
        #pragma unroll
        for (int j = 0; j < 8; ++j) v[j] = vs[kq * 8 + j][d];
        *(short8*)(vt + (((size_t)h * (S_LEN / 8) + kb * 4 + kq) * 128 + d) * 8) = v;
    }
}

// ---------------------------------------------------------------------------
// MFMA bf16 flash attention (causal), 2-phase pipelined + load-balanced.
//   Each block handles q-tile pair {p, 31-p} sequentially -> uniform 66
//   key-tile units per block (no causal tail). K/V staging double-buffered;
//   next tile's global_load_lds issued before computing current tile.
//   q: (S,H,192)  kv: (S,H,256) [k_nope|v]  abuf: (S,2112) k_pe@2048
//   vt: (H,S/8,128,8) pre-transposed V      attn: (S,H,128)
// ---------------------------------------------------------------------------
__global__ __launch_bounds__(256) void attn_mfma(
    const ushort_t* __restrict__ q,
    const ushort_t* __restrict__ kv,
    const ushort_t* __restrict__ abuf,
    const ushort_t* __restrict__ vt,
    ushort_t* __restrict__ attn)
{
    __shared__ short8 KF[2][768];   // 24 KB
    __shared__ short8 VF[2][512];   // 16 KB
    __shared__ short8 PA[256];      //  4 KB

    const int tid  = threadIdx.x;
    const int wave = tid >> 6;
    const int lane = tid & 63;
    const int m    = lane & 15;
    const int quad = lane >> 4;
    const int h    = blockIdx.y;
    const int pair = blockIdx.x;                  // 0..15
    const int qtiles[2] = { 31 - pair, pair };    // big tile first

    const float scale = 0.07216878364870323f; // 1/sqrt(192)
    short* pas = (short*)PA;

    auto stage_kv = [&](int t0, int buf) {
        #pragma unroll
        for (int rep = 0; rep < 3; ++rep) {
            int i   = rep * 256 + tid;
            int key = i & 31, qd = (i >> 5) & 3, c = i >> 7;   // c wave-uniform
            if (c < 4)
                GLOAD16(kv + ((size_t)(t0 + key) * NHEAD + h) * 256 + c * 32 + qd * 8,
                        &KF[buf][i]);
            else
                GLOAD16(abuf + (size_t)(t0 + key) * FUSED_N + 2048 + (c - 4) * 32 + qd * 8,
                        &KF[buf][i]);
        }
        const ushort_t* vsrc = vt + ((size_t)h * (S_LEN / 8) + (t0 >> 3)) * 1024;
        GLOAD16(vsrc + (size_t)tid * 8, &VF[buf][tid]);
        GLOAD16(vsrc + (size_t)(256 + tid) * 8, &VF[buf][256 + tid]);
    };

    for (int qi = 0; qi < 2; ++qi) {
        const int q0 = qtiles[qi] * 64;
        const int qrow_base = q0 + wave * 16;

        short8 qf[6];
        {
            const ushort_t* qrow = q + ((size_t)(qrow_base + m) * NHEAD + h) * QK_DIM;
            #pragma unroll
            for (int c = 0; c < 6; ++c)
                qf[c] = *(const short8*)(qrow + c * 32 + quad * 8);
        }

        floatx4 O[8];
        #pragma unroll
        for (int t = 0; t < 8; ++t) O[t] = (floatx4){0.f, 0.f, 0.f, 0.f};
        float mrow[4] = {-1e30f, -1e30f, -1e30f, -1e30f};
        float lrow[4] = {0.f, 0.f, 0.f, 0.f};

        const int ntile = (q0 + 64) / 32;

        stage_kv(0, 0);
        __syncthreads();
        int cur = 0;

        for (int tt = 0; tt < ntile; ++tt) {
            const int t0 = tt * 32;
            if (tt + 1 < ntile) stage_kv(t0 + 32, cur ^ 1);

            floatx4 s0 = (floatx4){0.f, 0.f, 0.f, 0.f};
            floatx4 s1 = (floatx4){0.f, 0.f, 0.f, 0.f};
            const int kb = quad * 32 + m;
            __builtin_amdgcn_s_setprio(1);
            #pragma unroll
            for (int c = 0; c < 6; ++c) {
                s0 = __builtin_amdgcn_mfma_f32_16x16x32_bf16(qf[c], KF[cur][c * 128 + kb],      s0, 0, 0, 0);
                s1 = __builtin_amdgcn_mfma_f32_16x16x32_bf16(qf[c], KF[cur][c * 128 + kb + 16], s1, 0, 0, 0);
            }
            __builtin_amdgcn_s_setprio(0);

            const int qb = qrow_base + quad * 4;
            float sv0[4], sv1[4];
            #pragma unroll
            for (int r = 0; r < 4; ++r) {
                float a0 = s0[r] * scale;
                float a1 = s1[r] * scale;
                if (t0 + m > qb + r)      a0 = -1e30f;
                if (t0 + 16 + m > qb + r) a1 = -1e30f;
                sv0[r] = a0; sv1[r] = a1;
            }
            #pragma unroll
            for (int r = 0; r < 4; ++r) {
                float v = fmaxf(sv0[r], sv1[r]);
                v = fmaxf(v, __shfl_xor(v, 1));
                v = fmaxf(v, __shfl_xor(v, 2));
                v = fmaxf(v, __shfl_xor(v, 4));
                v = fmaxf(v, __shfl_xor(v, 8));
                float mnew  = fmaxf(mrow[r], v);
                float alpha = __expf(mrow[r] - mnew);
                float p0 = __expf(sv0[r] - mnew);
                float p1 = __expf(sv1[r] - mnew);
                float rs = p0 + p1;
                rs += __shfl_xor(rs, 1);
                rs += __shfl_xor(rs, 2);
                rs += __shfl_xor(rs, 4);
                rs += __shfl_xor(rs, 8);
                lrow[r] = lrow[r] * alpha + rs;
                mrow[r] = mnew;
                #pragma unroll
                for (int t = 0; t < 8; ++t) O[t][r] *= alpha;
                int row = quad * 4 + r;
                short* pw = pas + wave * 512;
                pw[((m >> 3) + 0) * 128 + row * 8 + (m & 7)] = f2bf(p0);
                pw[((m >> 3) + 2) * 128 + row * 8 + (m & 7)] = f2bf(p1);
            }

            short8 pfrag = PA[wave * 64 + quad * 16 + m];
            __builtin_amdgcn_s_setprio(1);
            #pragma unroll
            for (int t = 0; t < 8; ++t) {
                O[t] = __builtin_amdgcn_mfma_f32_16x16x32_bf16(
                    pfrag, VF[cur][quad * 128 + m + 16 * t], O[t], 0, 0, 0);
            }
            __builtin_amdgcn_s_setprio(0);

            __syncthreads();   // drains vmcnt+lgkm: next buf staged, cur reads done
            cur ^= 1;
        }

        #pragma unroll
        for (int r = 0; r < 4; ++r) {
            float linv = 1.f / lrow[r];
            int row = qrow_base + quad * 4 + r;
            ushort_t* dst = attn + ((size_t)row * NHEAD + h) * VDIM + m;
            #pragma unroll
            for (int t = 0; t < 8; ++t)
                dst[16 * t] = (ushort_t)f2bf(O[t][r] * linv);
        }
        // PA is wave-private and rewritten each tile; KF/VF overwrite for the
        // next q-tile is fenced by the loop's trailing __syncthreads().
    }
}

// ---------------------------------------------------------------------------
extern "C" void kernel_launch(void* const* d_in, const int* in_sizes, int n_in,
                              void* d_out, int out_size, void* d_ws, size_t ws_size,
                              hipStream_t stream)
{
    const int*   pos    = (const int*)d_in[0];
    const float* hs     = (const float*)d_in[1];
    const float* w_a    = (const float*)d_in[2];
    const float* qlnw   = (const float*)d_in[3];
    const float* kvlnw  = (const float*)d_in[4];
    const float* w_qb   = (const float*)d_in[5];
    const float* w_kvb  = (const float*)d_in[6];
    const float* w_o    = (const float*)d_in[7];
    float* out = (float*)d_out;

    // workspace layout — all bf16, 146.0 MB total
    char* p = (char*)d_ws;
    ushort_t* a_bf    = (ushort_t*)p; p += (size_t)S_LEN * FUSED_N * 2;          //  8.65 MB
    ushort_t* q_bf    = (ushort_t*)p; p += (size_t)S_LEN * NHEAD * QK_DIM * 2;   // 25.2 MB
    ushort_t* kv_bf   = (ushort_t*)p; p += (size_t)S_LEN * NHEAD * 256 * 2;      // 33.6 MB
    ushort_t* attn_bf = (ushort_t*)p; p += (size_t)S_LEN * HID * 2;              // 16.8 MB
    ushort_t* hs_bf   = (ushort_t*)p; p += (size_t)S_LEN * HID * 2;              // 16.8 MB
    ushort_t* w_a_bf  = (ushort_t*)p; p += (size_t)FUSED_NPAD * HID * 2;         // 17.8 MB
    ushort_t* w_qb_bf = (ushort_t*)p; p += (size_t)NHEAD * QK_DIM * Q_LORA * 2;  // 18.9 MB
    ushort_t* w_kvb_bf= (ushort_t*)p; p += (size_t)NHEAD * 256 * KV_LORA * 2;    //  8.4 MB
    // w_o_bf (33.6 MB) aliases hs_bf + w_a_bf (34.6 MB), both dead after gemm 1
    ushort_t* w_o_bf  = hs_bf;
    // vt (16.8 MB) aliases w_qb_bf (18.9 MB), dead after gemm 3
    ushort_t* vt_bf   = w_qb_bf;

    if (ws_size < (size_t)(p - (char*)d_ws)) return;  // fail loud, not fault

    dim3 blk(256);
    auto cgrid = [](size_t n) { return dim3((unsigned)((n / 8 + 255) / 256)); };

    // 0. fp32 -> bf16 (hs + weights for gemms 1,3,4)
    conv_bf16<<<cgrid((size_t)S_LEN * HID), blk, 0, stream>>>(hs, hs_bf, S_LEN * HID);
    conv_bf16_pad<<<cgrid((size_t)FUSED_NPAD * HID), blk, 0, stream>>>(
        w_a, w_a_bf, FUSED_N * HID, FUSED_NPAD * HID);
    conv_bf16<<<cgrid((size_t)NHEAD * QK_DIM * Q_LORA), blk, 0, stream>>>(
        w_qb, w_qb_bf, NHEAD * QK_DIM * Q_LORA);
    conv_bf16<<<cgrid((size_t)NHEAD * 256 * KV_LORA), blk, 0, stream>>>(
        w_kvb, w_kvb_bf, NHEAD * 256 * KV_LORA);

    // 1. a = hs @ w_fused_a^T : (2048, 2112) bf16, K=4096
    gemm_bf16<ushort_t><<<dim3(FUSED_NPAD / 128, S_LEN / 128), blk, 0, stream>>>(
        hs_bf, HID, w_a_bf, HID, a_bf, FUSED_N, FUSED_N, HID);

    // 1b. w_o -> bf16 (into region freed by gemm 1)
    conv_bf16<<<cgrid((size_t)HID * HID), blk, 0, stream>>>(w_o, w_o_bf, HID * HID);

    // 2. RMSNorm cq / ckv + k_pe RoPE (in place, bf16)
    norm_rope_kernel<<<S_LEN, 256, 0, stream>>>(a_bf, qlnw, kvlnw, pos);

    // 3. q = cq @ w_q_b^T : (2048, 6144) bf16, K=1536
    gemm_bf16<ushort_t><<<dim3(NHEAD * QK_DIM / 128, S_LEN / 128), blk, 0, stream>>>(
        a_bf, FUSED_N, w_qb_bf, Q_LORA, q_bf, NHEAD * QK_DIM, NHEAD * QK_DIM, Q_LORA);

    // 4. kv = ckv @ w_kv_b^T : (2048, 8192) bf16, K=512
    gemm_bf16<ushort_t><<<dim3(NHEAD * 256 / 128, S_LEN / 128), blk, 0, stream>>>(
        a_bf + Q_LORA, FUSED_N, w_kvb_bf, KV_LORA, kv_bf, NHEAD * 256, NHEAD * 256, KV_LORA);

    // 4b. V pre-transpose into blocked (H, S/8, 128, 8) — w_qb region now dead
    transpose_v<<<dim3(S_LEN / 32, NHEAD), blk, 0, stream>>>(kv_bf, vt_bf);

    // 5. RoPE on q_pe (bf16 in place)
    rope_q_kernel<<<(S_LEN * NHEAD + 255) / 256, 256, 0, stream>>>(q_bf, pos);

    // 6. MFMA flash attention -> attn (2048, 32, 128) bf16
    //    grid: 16 balanced q-tile pairs x 32 heads
    attn_mfma<<<dim3(16, NHEAD), blk, 0, stream>>>(
        q_bf, kv_bf, a_bf, vt_bf, attn_bf);

    // 7. out = attn @ w_o^T : (2048, 4096) fp32, K=4096
    gemm_bf16<float><<<dim3(HID / 128, S_LEN / 128), blk, 0, stream>>>(
        attn_bf, HID, w_o_bf, HID, out, HID, HID, HID);
}

// Round 4
// 743.151 us; speedup vs baseline: 1.2389x; 1.0194x over previous
//
#include <hip/hip_runtime.h>
#include <cmath>

// Problem constants
#define S_LEN 2048
#define HID 4096
#define NHEAD 32
#define Q_LORA 1536
#define KV_LORA 512
#define NOPE 128
#define ROPE_D 64
#define VDIM 128
#define QK_DIM 192       // NOPE + ROPE
#define FUSED_N 2112     // Q_LORA + KV_LORA + ROPE
#define FUSED_NPAD 2176  // padded to a multiple of 128

typedef __attribute__((ext_vector_type(8))) short short8;
typedef __attribute__((ext_vector_type(4))) float floatx4;
typedef unsigned short ushort_t;

// float -> bf16 bits, round-to-nearest-even
__device__ inline short f2bf(float f) {
    union { float f; unsigned u; } v; v.f = f;
    unsigned r = (v.u + 0x7fffu + ((v.u >> 16) & 1u)) >> 16;
    return (short)r;
}
__device__ inline float bf2f(ushort_t u) {
    union { unsigned u; float f; } v; v.u = ((unsigned)u) << 16; return v.f;
}

// async 16B global -> LDS (LDS dest: wave-uniform base + lane*16)
#define GLOAD16(g, l)                                                        \
    __builtin_amdgcn_global_load_lds(                                        \
        (const __attribute__((address_space(1))) unsigned int*)(g),          \
        (__attribute__((address_space(3))) unsigned int*)(l), 16, 0, 0)

// ---------------------------------------------------------------------------
// fp32 -> bf16 converters (n % 8 == 0)
// ---------------------------------------------------------------------------
__global__ __launch_bounds__(256) void conv_bf16(
    const float* __restrict__ src, ushort_t* __restrict__ dst, int n)
{
    int i = (blockIdx.x * 256 + threadIdx.x) * 8;
    if (i >= n) return;
    const float4* s = (const float4*)(src + i);
    float4 a = s[0], b = s[1];
    short8 v;
    v[0] = f2bf(a.x); v[1] = f2bf(a.y); v[2] = f2bf(a.z); v[3] = f2bf(a.w);
    v[4] = f2bf(b.x); v[5] = f2bf(b.y); v[6] = f2bf(b.z); v[7] = f2bf(b.w);
    *(short8*)(dst + i) = v;
}

__global__ __launch_bounds__(256) void conv_bf16_pad(
    const float* __restrict__ src, ushort_t* __restrict__ dst, int n_src, int n_tot)
{
    int i = (blockIdx.x * 256 + threadIdx.x) * 8;
    if (i >= n_tot) return;
    short8 v;
    if (i < n_src) {
        const float4* s = (const float4*)(src + i);
        float4 a = s[0], b = s[1];
        v[0] = f2bf(a.x); v[1] = f2bf(a.y); v[2] = f2bf(a.z); v[3] = f2bf(a.w);
        v[4] = f2bf(b.x); v[5] = f2bf(b.y); v[6] = f2bf(b.z); v[7] = f2bf(b.w);
    } else {
        v = (short8){0,0,0,0,0,0,0,0};
    }
    *(short8*)(dst + i) = v;
}

// ---------------------------------------------------------------------------
// fp32 pairwise add (split-K reduce): o = p0 + p1
// ---------------------------------------------------------------------------
__global__ __launch_bounds__(256) void reduce_add_f32(
    const float* __restrict__ p0, const float* __restrict__ p1,
    float* __restrict__ o, int n)
{
    int i = (blockIdx.x * 256 + threadIdx.x) * 4;
    if (i >= n) return;
    float4 a = *(const float4*)(p0 + i);
    float4 b = *(const float4*)(p1 + i);
    float4 c; c.x = a.x + b.x; c.y = a.y + b.y; c.z = a.z + b.z; c.w = a.w + b.w;
    *(float4*)(o + i) = c;
}

// ---------------------------------------------------------------------------
// bf16 MFMA GEMM, 2-phase pipelined + optional split-K via blockIdx.z:
// C(M,N) = A(M,K) * B(N,K)^T, 128x128 tile, BK=32, 4 waves 2x2.
// Block z computes K-slice [z*Klen, (z+1)*Klen) and writes C-plane z
// (plane stride = gridDim.y*128*ldc). gridDim.z==1 => plain GEMM.
// ---------------------------------------------------------------------------
__device__ inline void store_c(float* p, float v)    { *p = v; }
__device__ inline void store_c(ushort_t* p, float v) { *p = (ushort_t)f2bf(v); }

template <typename CT>
__global__ __launch_bounds__(256) void gemm_bf16(
    const ushort_t* __restrict__ A, int lda,
    const ushort_t* __restrict__ B, int ldb,
    CT* __restrict__ C, int ldc, int N, int Klen)
{
    __shared__ short8 As8[2][512];   // 16 KB
    __shared__ short8 Bs8[2][512];   // 16 KB

    const int tid  = threadIdx.x;
    const int lane = tid & 63;
    const int wave = tid >> 6;
    const int m    = lane & 15;
    const int quad = lane >> 4;
    const int wr   = wave >> 1, wc = wave & 1;
    const int m0 = blockIdx.y * 128;
    const int n0 = blockIdx.x * 128;
    const int kbeg = blockIdx.z * Klen;
    const int kend = kbeg + Klen;
    CT* Cz = C + (size_t)blockIdx.z * (size_t)gridDim.y * 128 * ldc;

    floatx4 acc[4][4];
    #pragma unroll
    for (int i = 0; i < 4; ++i)
        #pragma unroll
        for (int j = 0; j < 4; ++j) acc[i][j] = (floatx4){0.f, 0.f, 0.f, 0.f};

    const int R0 = tid >> 6, q0s = (tid >> 4) & 3, e0 = tid & 15;
    const int R1 = (tid + 256) >> 6, q1s = ((tid + 256) >> 4) & 3, e1 = (tid + 256) & 15;

    auto stage = [&](int k0, int buf) {
        GLOAD16(A + (size_t)(m0 + R0 * 16 + e0) * lda + k0 + q0s * 8, &As8[buf][tid]);
        GLOAD16(A + (size_t)(m0 + R1 * 16 + e1) * lda + k0 + q1s * 8, &As8[buf][tid + 256]);
        GLOAD16(B + (size_t)(n0 + R0 * 16 + e0) * ldb + k0 + q0s * 8, &Bs8[buf][tid]);
        GLOAD16(B + (size_t)(n0 + R1 * 16 + e1) * ldb + k0 + q1s * 8, &Bs8[buf][tid + 256]);
    };

    stage(kbeg, 0);
    __syncthreads();
    int cur = 0;

    for (int k0 = kbeg; k0 < kend; k0 += 32) {
        if (k0 + 32 < kend) stage(k0 + 32, cur ^ 1);

        short8 af[4], bfr[4];
        #pragma unroll
        for (int i = 0; i < 4; ++i) af[i]  = As8[cur][((wr * 4 + i) * 4 + quad) * 16 + m];
        #pragma unroll
        for (int i = 0; i < 4; ++i) bfr[i] = Bs8[cur][((wc * 4 + i) * 4 + quad) * 16 + m];

        #pragma unroll
        for (int ri = 0; ri < 4; ++ri)
            #pragma unroll
            for (int ci = 0; ci < 4; ++ci)
                acc[ri][ci] = __builtin_amdgcn_mfma_f32_16x16x32_bf16(
                    af[ri], bfr[ci], acc[ri][ci], 0, 0, 0);

        __syncthreads();   // drains vmcnt(0)+lgkmcnt(0): next buf ready, cur reads done
        cur ^= 1;
    }

    #pragma unroll
    for (int ci = 0; ci < 4; ++ci) {
        int col = n0 + wc * 64 + ci * 16 + m;
        if (col < N) {
            #pragma unroll
            for (int ri = 0; ri < 4; ++ri) {
                int row = m0 + wr * 64 + ri * 16 + quad * 4;
                #pragma unroll
                for (int r = 0; r < 4; ++r)
                    store_c(&Cz[(size_t)(row + r) * ldc + col], acc[ri][ci][r]);
            }
        }
    }
}

// ---------------------------------------------------------------------------
// Fused split-K reduce + RMSNorm(cq), RMSNorm(ckv) + RoPE(k_pe).
// part: 2 fp32 planes of (S, FUSED_N); output a: bf16 (S, FUSED_N).
// RMS stats computed on fp32 sums (pre-rounding) — closer to reference.
// NOTE: ln-weight arrays are indexed RELATIVE to their segment
// (round-3 bug: kv_ln_w[Q_LORA + ...] read 4KB out of bounds).
// ---------------------------------------------------------------------------
__global__ __launch_bounds__(256) void norm_rope_kernel(
    const float* __restrict__ part,
    ushort_t* __restrict__ a,
    const float* __restrict__ q_ln_w,
    const float* __restrict__ kv_ln_w,
    const int* __restrict__ pos_ids)
{
    const int s = blockIdx.x;
    const float* r0 = part + (size_t)s * FUSED_N;
    const float* r1 = part + (size_t)S_LEN * FUSED_N + (size_t)s * FUSED_N;
    ushort_t* row = a + (size_t)s * FUSED_N;
    __shared__ float red[256];
    const int tid = threadIdx.x;

    // cq: 1536 = 6 * 256
    float vq[6];
    float ss = 0.f;
    #pragma unroll
    for (int j = 0; j < 6; ++j) {
        int i = tid + j * 256;
        vq[j] = r0[i] + r1[i];
        ss += vq[j] * vq[j];
    }
    red[tid] = ss;
    __syncthreads();
    for (int w = 128; w > 0; w >>= 1) {
        if (tid < w) red[tid] += red[tid + w];
        __syncthreads();
    }
    float scale_q = rsqrtf(red[0] / (float)Q_LORA + 1e-6f);
    #pragma unroll
    for (int j = 0; j < 6; ++j) {
        int i = tid + j * 256;
        row[i] = (ushort_t)f2bf(vq[j] * scale_q * q_ln_w[i]);
    }
    __syncthreads();

    // ckv: 512 = 2 * 256
    float vk[2];
    ss = 0.f;
    #pragma unroll
    for (int j = 0; j < 2; ++j) {
        int iw = tid + j * 256;                 // relative index in [0, 512)
        vk[j] = r0[Q_LORA + iw] + r1[Q_LORA + iw];
        ss += vk[j] * vk[j];
    }
    red[tid] = ss;
    __syncthreads();
    for (int w = 128; w > 0; w >>= 1) {
        if (tid < w) red[tid] += red[tid + w];
        __syncthreads();
    }
    float scale_kv = rsqrtf(red[0] / (float)KV_LORA + 1e-6f);
    #pragma unroll
    for (int j = 0; j < 2; ++j) {
        int iw = tid + j * 256;
        row[Q_LORA + iw] = (ushort_t)f2bf(vk[j] * scale_kv * kv_ln_w[iw]);
    }

    // k_pe RoPE on fp32 sums
    if (tid < 32) {
        const int j = tid;
        float pos = (float)pos_ids[s];
        float inv_freq = expf(-(float)j * (9.210340371976184f / 32.f));
        float ang = pos * inv_freq;
        float c = cosf(ang), sn = sinf(ang);
        float x1 = r0[Q_LORA + KV_LORA + j]      + r1[Q_LORA + KV_LORA + j];
        float x2 = r0[Q_LORA + KV_LORA + 32 + j] + r1[Q_LORA + KV_LORA + 32 + j];
        row[Q_LORA + KV_LORA + j]      = (ushort_t)f2bf(x1 * c - x2 * sn);
        row[Q_LORA + KV_LORA + 32 + j] = (ushort_t)f2bf(x2 * c + x1 * sn);
    }
}

// ---------------------------------------------------------------------------
// RoPE on q_pe (bf16 in place): q is (S*H, 192), rope dims [128,192)
// ---------------------------------------------------------------------------
__global__ __launch_bounds__(256) void rope_q_kernel(
    ushort_t* __restrict__ q, const int* __restrict__ pos_ids)
{
    int idx = blockIdx.x * blockDim.x + threadIdx.x;
    if (idx >= S_LEN * NHEAD) return;
    int s = idx >> 5;
    float pos = (float)pos_ids[s];
    ushort_t* qp = q + (size_t)idx * QK_DIM + NOPE;
    #pragma unroll 4
    for (int j = 0; j < 32; ++j) {
        float inv_freq = expf(-(float)j * (9.210340371976184f / 32.f));
        float ang = pos * inv_freq;
        float c = cosf(ang), sn = sinf(ang);
        float x1 = bf2f(qp[j]), x2 = bf2f(qp[32 + j]);
        qp[j]      = (ushort_t)f2bf(x1 * c - x2 * sn);
        qp[32 + j] = (ushort_t)f2bf(x2 * c + x1 * sn);
    }
}

// ---------------------------------------------------------------------------
// V pre-transpose: kv (S, H, 256) bf16, v part [128,256) -> vt blocked
// (H, S/8, 128, 8) bf16:  vt[h][g][d][j] = v[key = g*8+j][d]
// ---------------------------------------------------------------------------
__global__ __launch_bounds__(256) void transpose_v(
    const ushort_t* __restrict__ kv, ushort_t* __restrict__ vt)
{
    __shared__ ushort_t vs[32][128];   // 8 KB
    const int tid = threadIdx.x;
    const int h   = blockIdx.y;
    const int kb  = blockIdx.x;        // block of 32 keys

    #pragma unroll
    for (int rep = 0; rep < 2; ++rep) {
        int i = rep * 256 + tid;
        int key = i >> 4, ch = i & 15;
        *(short8*)&vs[key][ch * 8] =
            *(const short8*)(kv + ((size_t)(kb * 32 + key) * NHEAD + h) * 256 + 128 + ch * 8);
    }
    __syncthreads();
    #pragma unroll
    for (int rep = 0; rep < 2; ++rep) {
        int i = rep * 256 + tid;
        int kq = i >> 7, d = i & 127;
        short8 v;
        #pragma unroll
        for (int j = 0; j < 8; ++j) v[j] = vs[kq * 8 + j][d];
        *(short8*)(vt + (((size_t)h * (S_LEN / 8) + kb * 4 + kq) * 128 + d) * 8) = v;
    }
}

// ---------------------------------------------------------------------------
// MFMA bf16 flash attention (causal), 2-phase pipelined + load-balanced.
//   Block handles q-tile pair {31-p, p} -> uniform 66 key-tiles per block.
//   Softmax: defer-max (THR=8) skips O-rescale when tile max doesn't grow;
//   l kept as per-lane partial, reduced once at the end (alpha is uniform
//   across the 16-lane row-group, so per-lane rescale is exact).
// ---------------------------------------------------------------------------
__global__ __launch_bounds__(256) void attn_mfma(
    const ushort_t* __restrict__ q,
    const ushort_t* __restrict__ kv,
    const ushort_t* __restrict__ abuf,
    const ushort_t* __restrict__ vt,
    ushort_t* __restrict__ attn)
{
    __shared__ short8 KF[2][768];   // 24 KB
    __shared__ short8 VF[2][512];   // 16 KB
    __shared__ short8 PA[256];      //  4 KB

    const int tid  = threadIdx.x;
    const int wave = tid >> 6;
    const int lane = tid & 63;
    const int m    = lane & 15;
    const int quad = lane >> 4;
    const int h    = blockIdx.y;
    const int pair = blockIdx.x;                  // 0..15
    const int qtiles[2] = { 31 - pair, pair };    // big tile first

    const float scale = 0.07216878364870323f; // 1/sqrt(192)
    short* pas = (short*)PA;

    auto stage_kv = [&](int t0, int buf) {
        #pragma unroll
        for (int rep = 0; rep < 3; ++rep) {
            int i   = rep * 256 + tid;
            int key = i & 31, qd = (i >> 5) & 3, c = i >> 7;   // c wave-uniform
            if (c < 4)
                GLOAD16(kv + ((size_t)(t0 + key) * NHEAD + h) * 256 + c * 32 + qd * 8,
                        &KF[buf][i]);
            else
                GLOAD16(abuf + (size_t)(t0 + key) * FUSED_N + 2048 + (c - 4) * 32 + qd * 8,
                        &KF[buf][i]);
        }
        const ushort_t* vsrc = vt + ((size_t)h * (S_LEN / 8) + (t0 >> 3)) * 1024;
        GLOAD16(vsrc + (size_t)tid * 8, &VF[buf][tid]);
        GLOAD16(vsrc + (size_t)(256 + tid) * 8, &VF[buf][256 + tid]);
    };

    for (int qi = 0; qi < 2; ++qi) {
        const int q0 = qtiles[qi] * 64;
        const int qrow_base = q0 + wave * 16;

        short8 qf[6];
        {
            const ushort_t* qrow = q + ((size_t)(qrow_base + m) * NHEAD + h) * QK_DIM;
            #pragma unroll
            for (int c = 0; c < 6; ++c)
                qf[c] = *(const short8*)(qrow + c * 32 + quad * 8);
        }

        floatx4 O[8];
        #pragma unroll
        for (int t = 0; t < 8; ++t) O[t] = (floatx4){0.f, 0.f, 0.f, 0.f};
        float mrow[4] = {-1e30f, -1e30f, -1e30f, -1e30f};
        float lrow[4] = {0.f, 0.f, 0.f, 0.f};

        const int ntile = (q0 + 64) / 32;

        stage_kv(0, 0);
        __syncthreads();
        int cur = 0;

        for (int tt = 0; tt < ntile; ++tt) {
            const int t0 = tt * 32;
            if (tt + 1 < ntile) stage_kv(t0 + 32, cur ^ 1);

            floatx4 s0 = (floatx4){0.f, 0.f, 0.f, 0.f};
            floatx4 s1 = (floatx4){0.f, 0.f, 0.f, 0.f};
            const int kb = quad * 32 + m;
            __builtin_amdgcn_s_setprio(1);
            #pragma unroll
            for (int c = 0; c < 6; ++c) {
                s0 = __builtin_amdgcn_mfma_f32_16x16x32_bf16(qf[c], KF[cur][c * 128 + kb],      s0, 0, 0, 0);
                s1 = __builtin_amdgcn_mfma_f32_16x16x32_bf16(qf[c], KF[cur][c * 128 + kb + 16], s1, 0, 0, 0);
            }
            __builtin_amdgcn_s_setprio(0);

            const int qb = qrow_base + quad * 4;
            float sv0[4], sv1[4];
            #pragma unroll
            for (int r = 0; r < 4; ++r) {
                float a0 = s0[r] * scale;
                float a1 = s1[r] * scale;
                if (t0 + m > qb + r)      a0 = -1e30f;
                if (t0 + 16 + m > qb + r) a1 = -1e30f;
                sv0[r] = a0; sv1[r] = a1;
            }
            #pragma unroll
            for (int r = 0; r < 4; ++r) {
                float v = fmaxf(sv0[r], sv1[r]);
                v = fmaxf(v, __shfl_xor(v, 1));
                v = fmaxf(v, __shfl_xor(v, 2));
                v = fmaxf(v, __shfl_xor(v, 4));
                v = fmaxf(v, __shfl_xor(v, 8));
                // defer-max: only rescale when the running max grows by >8;
                // otherwise P values stay bounded by e^8 (bf16-safe).
                if (v > mrow[r] + 8.f) {
                    float alpha = __expf(mrow[r] - v);   // first tile: exp(-inf)=0
                    lrow[r] *= alpha;
                    #pragma unroll
                    for (int t = 0; t < 8; ++t) O[t][r] *= alpha;
                    mrow[r] = v;
                }
                float p0 = __expf(sv0[r] - mrow[r]);
                float p1 = __expf(sv1[r] - mrow[r]);
                lrow[r] += p0 + p1;                      // per-lane partial
                int row = quad * 4 + r;
                short* pw = pas + wave * 512;
                pw[((m >> 3) + 0) * 128 + row * 8 + (m & 7)] = f2bf(p0);
                pw[((m >> 3) + 2) * 128 + row * 8 + (m & 7)] = f2bf(p1);
            }

            short8 pfrag = PA[wave * 64 + quad * 16 + m];
            __builtin_amdgcn_s_setprio(1);
            #pragma unroll
            for (int t = 0; t < 8; ++t) {
                O[t] = __builtin_amdgcn_mfma_f32_16x16x32_bf16(
                    pfrag, VF[cur][quad * 128 + m + 16 * t], O[t], 0, 0, 0);
            }
            __builtin_amdgcn_s_setprio(0);

            __syncthreads();   // drains vmcnt+lgkm: next buf staged, cur reads done
            cur ^= 1;
        }

        #pragma unroll
        for (int r = 0; r < 4; ++r) {
            float l = lrow[r];                           // reduce once at the end
            l += __shfl_xor(l, 1);
            l += __shfl_xor(l, 2);
            l += __shfl_xor(l, 4);
            l += __shfl_xor(l, 8);
            float linv = 1.f / l;
            int row = qrow_base + quad * 4 + r;
            ushort_t* dst = attn + ((size_t)row * NHEAD + h) * VDIM + m;
            #pragma unroll
            for (int t = 0; t < 8; ++t)
                dst[16 * t] = (ushort_t)f2bf(O[t][r] * linv);
        }
    }
}

// ---------------------------------------------------------------------------
extern "C" void kernel_launch(void* const* d_in, const int* in_sizes, int n_in,
                              void* d_out, int out_size, void* d_ws, size_t ws_size,
                              hipStream_t stream)
{
    const int*   pos    = (const int*)d_in[0];
    const float* hs     = (const float*)d_in[1];
    const float* w_a    = (const float*)d_in[2];
    const float* qlnw   = (const float*)d_in[3];
    const float* kvlnw  = (const float*)d_in[4];
    const float* w_qb   = (const float*)d_in[5];
    const float* w_kvb  = (const float*)d_in[6];
    const float* w_o    = (const float*)d_in[7];
    float* out = (float*)d_out;

    // workspace layout — all bf16, 146.0 MB total
    char* p = (char*)d_ws;
    ushort_t* a_bf    = (ushort_t*)p; p += (size_t)S_LEN * FUSED_N * 2;          //  8.65 MB
    ushort_t* q_bf    = (ushort_t*)p; p += (size_t)S_LEN * NHEAD * QK_DIM * 2;   // 25.2 MB
    ushort_t* kv_bf   = (ushort_t*)p; p += (size_t)S_LEN * NHEAD * 256 * 2;      // 33.6 MB
    ushort_t* attn_bf = (ushort_t*)p; p += (size_t)S_LEN * HID * 2;              // 16.8 MB
    ushort_t* hs_bf   = (ushort_t*)p; p += (size_t)S_LEN * HID * 2;              // 16.8 MB
    ushort_t* w_a_bf  = (ushort_t*)p; p += (size_t)FUSED_NPAD * HID * 2;         // 17.8 MB
    ushort_t* w_qb_bf = (ushort_t*)p; p += (size_t)NHEAD * QK_DIM * Q_LORA * 2;  // 18.9 MB
    ushort_t* w_kvb_bf= (ushort_t*)p; p += (size_t)NHEAD * 256 * KV_LORA * 2;    //  8.4 MB
    // w_o_bf (33.6 MB) aliases hs_bf + w_a_bf (34.6 MB), both dead after gemm 1
    ushort_t* w_o_bf  = hs_bf;
    // vt (16.8 MB) aliases w_qb_bf (18.9 MB), dead after gemm 3
    ushort_t* vt_bf   = w_qb_bf;
    // gemm1 split-K fp32 partials (34.6 MB): q_bf+kv_bf region (58.7 MB),
    // consumed by norm_rope before gemm3 writes q_bf.
    float* part1 = (float*)q_bf;
    // gemm7 split-K fp32 partials (67.1 MB): a_bf+q_bf+kv_bf region (67.37 MB),
    // all dead after attn.
    float* part7 = (float*)a_bf;

    if (ws_size < (size_t)(p - (char*)d_ws)) return;  // fail loud, not fault

    dim3 blk(256);
    auto cgrid = [](size_t n) { return dim3((unsigned)((n / 8 + 255) / 256)); };

    // 0. fp32 -> bf16 (hs + weights for gemms 1,3,4)
    conv_bf16<<<cgrid((size_t)S_LEN * HID), blk, 0, stream>>>(hs, hs_bf, S_LEN * HID);
    conv_bf16_pad<<<cgrid((size_t)FUSED_NPAD * HID), blk, 0, stream>>>(
        w_a, w_a_bf, FUSED_N * HID, FUSED_NPAD * HID);
    conv_bf16<<<cgrid((size_t)NHEAD * QK_DIM * Q_LORA), blk, 0, stream>>>(
        w_qb, w_qb_bf, NHEAD * QK_DIM * Q_LORA);
    conv_bf16<<<cgrid((size_t)NHEAD * 256 * KV_LORA), blk, 0, stream>>>(
        w_kvb, w_kvb_bf, NHEAD * 256 * KV_LORA);

    // 1. a = hs @ w_fused_a^T : split-K=2, fp32 partials (2048, 2112) x2
    gemm_bf16<float><<<dim3(FUSED_NPAD / 128, S_LEN / 128, 2), blk, 0, stream>>>(
        hs_bf, HID, w_a_bf, HID, part1, FUSED_N, FUSED_N, HID / 2);

    // 1b. w_o -> bf16 (into region freed by gemm 1)
    conv_bf16<<<cgrid((size_t)HID * HID), blk, 0, stream>>>(w_o, w_o_bf, HID * HID);

    // 2. fused split-K reduce + RMSNorm cq/ckv + k_pe RoPE -> a_bf
    norm_rope_kernel<<<S_LEN, 256, 0, stream>>>(part1, a_bf, qlnw, kvlnw, pos);

    // 3. q = cq @ w_q_b^T : (2048, 6144) bf16, K=1536 (overwrites part1 region)
    gemm_bf16<ushort_t><<<dim3(NHEAD * QK_DIM / 128, S_LEN / 128), blk, 0, stream>>>(
        a_bf, FUSED_N, w_qb_bf, Q_LORA, q_bf, NHEAD * QK_DIM, NHEAD * QK_DIM, Q_LORA);

    // 4. kv = ckv @ w_kv_b^T : (2048, 8192) bf16, K=512
    gemm_bf16<ushort_t><<<dim3(NHEAD * 256 / 128, S_LEN / 128), blk, 0, stream>>>(
        a_bf + Q_LORA, FUSED_N, w_kvb_bf, KV_LORA, kv_bf, NHEAD * 256, NHEAD * 256, KV_LORA);

    // 4b. V pre-transpose into blocked (H, S/8, 128, 8) — w_qb region now dead
    transpose_v<<<dim3(S_LEN / 32, NHEAD), blk, 0, stream>>>(kv_bf, vt_bf);

    // 5. RoPE on q_pe (bf16 in place)
    rope_q_kernel<<<(S_LEN * NHEAD + 255) / 256, 256, 0, stream>>>(q_bf, pos);

    // 6. MFMA flash attention -> attn (2048, 32, 128) bf16
    attn_mfma<<<dim3(16, NHEAD), blk, 0, stream>>>(
        q_bf, kv_bf, a_bf, vt_bf, attn_bf);

    // 7. out = attn @ w_o^T : split-K=2, fp32 partials (2048, 4096) x2, then add
    gemm_bf16<float><<<dim3(HID / 128, S_LEN / 128, 2), blk, 0, stream>>>(
        attn_bf, HID, w_o_bf, HID, part7, HID, HID, HID / 2);
    reduce_add_f32<<<cgrid((size_t)S_LEN * HID * 2), blk, 0, stream>>>(
        part7, part7 + (size_t)S_LEN * HID, out, S_LEN * HID);
}